// Round 2
// baseline (333.752 us; speedup 1.0000x reference)
//
#include <hip/hip_runtime.h>

// moment[i] = interval * D[i], where
//   S[i] = sum_{j<i} f[j]              (exclusive shear)
//   D[i] = sum_{j<i} S[j]              (exclusive double-sum)
// Linear scan state (S, D); appending a segment with (s = sum f, d = sum of
// local exclusive shears, n elements):  S' = S + s ;  D' = D + n*S + d.
// All accumulation in f64 (f32 reference has ulp ~1e4 at |D|~1e11; f64 is
// strictly more accurate, diff vs reference = reference's own rounding noise).

constexpr int BLOCK = 256;
constexpr int ITEMS = 16;                 // elems per thread
constexpr int TILE  = BLOCK * ITEMS;      // 4096 elems per block

struct Agg { double s; double d; };

// Inclusive Hillis-Steele pair-scan across BLOCK threads (LDS).
// Each thread contributes (s, d) over n_items elements.
// Outputs: exclusive prefix (se, de) for this thread, and block totals.
__device__ inline void block_pair_scan(double s, double d, double n_items,
                                       double& se, double& de,
                                       double& stot, double& dtot)
{
    __shared__ double ls[BLOCK], ld[BLOCK], ln[BLOCK];
    const int t = threadIdx.x;
    ls[t] = s; ld[t] = d; ln[t] = n_items;
    __syncthreads();
#pragma unroll
    for (int o = 1; o < BLOCK; o <<= 1) {
        double cs = ls[t], cd = ld[t], cn = ln[t];
        double sl = 0.0, dl = 0.0, nl = 0.0;
        if (t >= o) { sl = ls[t - o]; dl = ld[t - o]; nl = ln[t - o]; }
        __syncthreads();
        if (t >= o) {
            cd = dl + cn * sl + cd;   // D_left + n_right*S_left + D_right
            cs = sl + cs;
            cn = nl + cn;
        }
        ls[t] = cs; ld[t] = cd; ln[t] = cn;
        __syncthreads();
    }
    se = (t == 0) ? 0.0 : ls[t - 1];
    de = (t == 0) ? 0.0 : ld[t - 1];
    stot = ls[BLOCK - 1];
    dtot = ld[BLOCK - 1];
}

// K1: per-block aggregates (s, d) -> agg[blockIdx]
__global__ __launch_bounds__(BLOCK) void k_partial(const float* __restrict__ f,
                                                   Agg* __restrict__ agg)
{
    const size_t base = (size_t)blockIdx.x * TILE + (size_t)threadIdx.x * ITEMS;
    const float4* p = reinterpret_cast<const float4*>(f + base);
    double s = 0.0, d = 0.0;
#pragma unroll
    for (int i = 0; i < ITEMS / 4; ++i) {
        float4 v = p[i];
        d += s; s += (double)v.x;
        d += s; s += (double)v.y;
        d += s; s += (double)v.z;
        d += s; s += (double)v.w;
    }
    double se, de, st, dt;
    block_pair_scan(s, d, (double)ITEMS, se, de, st, dt);
    if (threadIdx.x == 0) { agg[blockIdx.x].s = st; agg[blockIdx.x].d = dt; }
}

// K2: single block converts agg[] (per-block totals) to exclusive offsets, in place.
__global__ __launch_bounds__(BLOCK) void k_scan_aggs(Agg* __restrict__ agg, int nblocks)
{
    const int t  = threadIdx.x;
    const int ch = nblocks / BLOCK;           // aggregates per thread
    const int lo = t * ch;
    double s = 0.0, d = 0.0;
    for (int i = 0; i < ch; ++i) {
        Agg a = agg[lo + i];
        d += (double)TILE * s + a.d;          // uses old s
        s += a.s;
    }
    double se, de, st, dt;
    block_pair_scan(s, d, (double)ch * (double)TILE, se, de, st, dt);
    double S = se, D = de;
    for (int i = 0; i < ch; ++i) {
        Agg a = agg[lo + i];
        agg[lo + i].s = S;
        agg[lo + i].d = D;
        D += (double)TILE * S + a.d;          // uses old S
        S += a.s;
    }
}

// K3: re-read forces, rebuild local scans, add block offset, emit outputs.
__global__ __launch_bounds__(BLOCK) void k_emit(const float* __restrict__ f,
                                                const Agg* __restrict__ agg,
                                                const float* __restrict__ interval,
                                                float* __restrict__ out)
{
    const size_t base = (size_t)blockIdx.x * TILE + (size_t)threadIdx.x * ITEMS;
    const float4* p = reinterpret_cast<const float4*>(f + base);
    float4 v[ITEMS / 4];
#pragma unroll
    for (int i = 0; i < ITEMS / 4; ++i) v[i] = p[i];

    double s = 0.0, d = 0.0;
#pragma unroll
    for (int i = 0; i < ITEMS / 4; ++i) {
        d += s; s += (double)v[i].x;
        d += s; s += (double)v[i].y;
        d += s; s += (double)v[i].z;
        d += s; s += (double)v[i].w;
    }
    double se, de, st, dt;
    block_pair_scan(s, d, (double)ITEMS, se, de, st, dt);

    const Agg off = agg[blockIdx.x];
    double S = off.s + se;
    double D = off.d + (double)(threadIdx.x * ITEMS) * off.s + de;
    const double itv = (double)interval[0];

    float4* po = reinterpret_cast<float4*>(out + base);
#pragma unroll
    for (int i = 0; i < ITEMS / 4; ++i) {
        float4 o;
        o.x = (float)(itv * D); D += S; S += (double)v[i].x;
        o.y = (float)(itv * D); D += S; S += (double)v[i].y;
        o.z = (float)(itv * D); D += S; S += (double)v[i].z;
        o.w = (float)(itv * D); D += S; S += (double)v[i].w;
        po[i] = o;
    }
}

extern "C" void kernel_launch(void* const* d_in, const int* in_sizes, int n_in,
                              void* d_out, int out_size, void* d_ws, size_t ws_size,
                              hipStream_t stream)
{
    const float* forces   = (const float*)d_in[0];
    // d_in[1] = positions: unused by moment()
    const float* interval = (const float*)d_in[2];
    float* out = (float*)d_out;

    const int P = in_sizes[0];
    const int nblocks = P / TILE;             // 2^25 / 4096 = 8192

    Agg* agg = (Agg*)d_ws;                    // 8192 * 16 B = 128 KiB scratch

    hipLaunchKernelGGL(k_partial,   dim3(nblocks), dim3(BLOCK), 0, stream, forces, agg);
    hipLaunchKernelGGL(k_scan_aggs, dim3(1),       dim3(BLOCK), 0, stream, agg, nblocks);
    hipLaunchKernelGGL(k_emit,      dim3(nblocks), dim3(BLOCK), 0, stream, forces, agg, interval, out);
}